// Round 7
// baseline (119.117 us; speedup 1.0000x reference)
//
#include <hip/hip_runtime.h>
#include <math.h>

// One thread per batch element for eig + layer0 + reconstruction.
// Middle layers (23x23, id + sum path) and layer 3 run on the MATRIX pipe.
// Each 64-thread block is ONE wave, fully self-contained, no __syncthreads
// (a wave's DS ops execute in order).
//
// Numerics note (round-6 failure): the spectral reconstruction is node-exact,
// so f16 MLP noise eps is NOT gap-amplified -- but a node perturbation delta
// (from an inaccurate acos) couples as delta*(eps/gap) over 524k samples.
// Hence acos must be accurate: A&S 4.4.46 degree-7 sqrt-form minimax
// (|err|<=2e-8 rad) -- node error negligible, still ~25 fewer serial VALU ops
// than libm acosf.
// - Bias folded into the MFMA: A(Ws)[row][k=23] = bias[row], hidden state
//   carries 1.0 at (row 23, channel t0). Exact (biases are zero here anyway).
// - Output written as 2x dwordx4 + 1 dword.

#define MLP_W 23

typedef _Float16 h2    __attribute__((ext_vector_type(2)));
typedef _Float16 f16x4 __attribute__((ext_vector_type(4)));
typedef _Float16 f16x8 __attribute__((ext_vector_type(8)));
typedef float    f32x4 __attribute__((ext_vector_type(4)));
typedef float    v2f   __attribute__((ext_vector_type(2)));
typedef float    f4a   __attribute__((ext_vector_type(4), aligned(4)));

// A-fragments for the two middle layers (mfma_f32_16x16x32_f16):
// lane l holds A[row = mt*16 + (l&15)][k = 8*(l>>4) + e], e=0..7, zero past 22,
// EXCEPT Ws k=23 column = bias (bias-in-MFMA trick).
__device__ __attribute__((aligned(16))) h2 g_afrag[2][2][2][64][4];
// layer-3 A-fragment: row 0 = wi3, row 1 = ws3, rows 2..15 zero (k=23 -> 0).
__device__ __attribute__((aligned(16))) h2 g_a3frag[64][4];
// layer-0 weights, zero-padded to 24 for pair loads: [0]=wi, [1]=ws, [2]=b
__device__ __attribute__((aligned(16))) float g_l0[3][24];

__global__ void svh_prep_kernel(const float* __restrict__ wi0, const float* __restrict__ ws0,
                                const float* __restrict__ b0,
                                const float* __restrict__ wi1, const float* __restrict__ ws1,
                                const float* __restrict__ b1,
                                const float* __restrict__ wi2, const float* __restrict__ ws2,
                                const float* __restrict__ b2,
                                const float* __restrict__ wi3, const float* __restrict__ ws3) {
    int t = blockIdx.x * blockDim.x + threadIdx.x;
    if (t < 512) {   // one thread per [layer][mat][mtile][lane]
        int lane  = t & 63;
        int mt    = (t >> 6) & 1;
        int mat   = (t >> 7) & 1;
        int layer = (t >> 8) & 1;
        const float* W  = layer ? (mat ? ws2 : wi2) : (mat ? ws1 : wi1);
        const float* BI = layer ? b2 : b1;
        int row = mt * 16 + (lane & 15);
        int g   = lane >> 4;
#pragma unroll
        for (int dw = 0; dw < 4; ++dw) {
            int k0 = 8 * g + 2 * dw, k1 = k0 + 1;
            float a = (row < MLP_W && k0 < MLP_W) ? W[row * MLP_W + k0] : 0.0f;
            float b = (row < MLP_W && k1 < MLP_W) ? W[row * MLP_W + k1] : 0.0f;
            // bias column: Ws matrix, k=23 slot carries bias[row]
            if (mat == 1 && k1 == 23 && row < MLP_W) b = BI[row];
            g_afrag[layer][mat][mt][lane][dw] = (h2){(_Float16)a, (_Float16)b};
        }
    }
    if (t < 64) {
        int lane = t;
        int row  = lane & 15;
        int g    = lane >> 4;
#pragma unroll
        for (int dw = 0; dw < 4; ++dw) {
            int k0 = 8 * g + 2 * dw, k1 = k0 + 1;
            float a = 0.0f, b = 0.0f;
            if (row == 0) {
                a = (k0 < MLP_W) ? wi3[k0] : 0.0f;
                b = (k1 < MLP_W) ? wi3[k1] : 0.0f;
            } else if (row == 1) {
                a = (k0 < MLP_W) ? ws3[k0] : 0.0f;
                b = (k1 < MLP_W) ? ws3[k1] : 0.0f;
            }
            g_a3frag[lane][dw] = (h2){(_Float16)a, (_Float16)b};
        }
    }
    if (t < 24) {
        g_l0[0][t] = (t < MLP_W) ? wi0[t] : 0.0f;
        g_l0[1][t] = (t < MLP_W) ? ws0[t] : 0.0f;
        g_l0[2][t] = (t < MLP_W) ? b0[t]  : 0.0f;
    }
}

__device__ __forceinline__ float sinv(float d) {
    return (fabsf(d) > 1e-20f) ? (1.0f / d) : 0.0f;
}

__device__ __forceinline__ f32x4 mm16(f16x8 a, f16x8 b) {
    return __builtin_amdgcn_mfma_f32_16x16x32_f16(a, b, (f32x4){0.f, 0.f, 0.f, 0.f}, 0, 0, 0);
}
__device__ __forceinline__ f32x4 mm16a(f16x8 a, f16x8 b, f32x4 c) {
    return __builtin_amdgcn_mfma_f32_16x16x32_f16(a, b, c, 0, 0, 0);
}

// LDS: per column (=lane), 3 k-chunks x 3 channels x 16B, col stride 144
// (16-aligned). chunk g' holds k=8g'..8g'+7 (f16x8) of channel h at
// col*144 + g'*48 + h*16. k=24..31 fragment group reads a 16B zero block.
#define COLB 144
#define ZOFF (64 * COLB)    // 9216
#define LDSZ (ZOFF + 16)    // 9232

__global__ __launch_bounds__(64, 4)
void svh_eig_mlp_kernel(
    const float* __restrict__ x,
    const float* __restrict__ bb3,
    float* __restrict__ out, int B)
{
    __shared__ alignas(16) unsigned char lds[LDSZ];

    const int lane = threadIdx.x;           // 0..63, one wave per block
    const int g    = lane >> 4;
    const int c16  = lane & 15;
    int idx  = blockIdx.x * 64 + lane;
    int cidx = (idx < B) ? idx : (B - 1);   // NO early return: cooperative MFMA

    const float* xp = x + (size_t)cidx * 9;
    f4a xa = *(const f4a*)(xp);       // x[0..3]
    f4a xb = *(const f4a*)(xp + 4);   // x[4..7]
    float x22 = xp[8];
    float x00 = xa[0], x01 = xa[1], x02 = xa[2];
    float x11 = xb[0], x12 = xb[1];

    // zero block for the k=24..31 fragment group (same-wave DS => ordered)
    if (lane == 0) *(f32x4*)(lds + ZOFF) = (f32x4){0.f, 0.f, 0.f, 0.f};

    // ---- closed-form symmetric 3x3 eigenvalues (trigonometric method) ----
    float q   = (x00 + x11 + x22) * (1.0f / 3.0f);
    float a00 = x00 - q, a11 = x11 - q, a22 = x22 - q;
    float p1  = x01 * x01 + x02 * x02 + x12 * x12;
    float p2  = a00 * a00 + a11 * a11 + a22 * a22 + 2.0f * p1;
    float p   = sqrtf(p2 * (1.0f / 6.0f));
    float ip  = sinv(p);
    float d00 = a00 * ip, d11 = a11 * ip, d22 = a22 * ip;
    float c01 = x01 * ip, c02 = x02 * ip, c12 = x12 * ip;
    float detB = d00 * (d11 * d22 - c12 * c12)
               - c01 * (c01 * d22 - c12 * c02)
               + c02 * (c01 * c12 - d11 * c02);
    float r = 0.5f * detB;
    r = fminf(1.0f, fmaxf(-1.0f, r));
    // acos via A&S 4.4.46 degree-7 sqrt-form minimax, |err| <= 2e-8 rad.
    // (Round-6 lesson: node error delta couples as delta*(eps_f16/gap); the
    // degree-3 poly's 6.8e-5 rad was 3000x too coarse. This one is exact
    // enough that the coupling term is ~1e-5.)
    float ar  = fabsf(r);
    float sq  = sqrtf(fmaxf(0.0f, 1.0f - ar));
    float po  = fmaf(ar, -0.0012624911f, 0.0066700901f);
    po = fmaf(ar, po, -0.0170881256f);
    po = fmaf(ar, po,  0.0308918810f);
    po = fmaf(ar, po, -0.0501743046f);
    po = fmaf(ar, po,  0.0889789874f);
    po = fmaf(ar, po, -0.2145988016f);
    po = fmaf(ar, po,  1.5707963050f);
    float acs = sq * po * (1.0f / 3.0f);        // acos(|r|)/3
    const float PI3 = 1.0471975511965976f;      // pi/3
    float phi = (r >= 0.0f) ? acs : (PI3 - acs);
    float cph  = __cosf(phi);
    float sph  = sqrtf(fmaxf(0.0f, 1.0f - cph * cph)); // sin(phi) >= 0
    const float SQ3 = 1.7320508075688772f;
    float lc = q + 2.0f * p * cph;
    float la = q - p * cph - SQ3 * p * sph;
    float lb = q - p * cph + SQ3 * p * sph;

    // ---- layer 0 (ic=1): packed-f32 pairs, write own 3-channel column ----
    {
        float S = la + lb + lc;
        v2f Sv = {S, S}, lav = {la, la}, lbv = {lb, lb}, lcv = {lc, lc};
        v2f z2 = {0.f, 0.f};
        const v2f* L0WI = (const v2f*)g_l0[0];
        const v2f* L0WS = (const v2f*)g_l0[1];
        const v2f* L0BB = (const v2f*)g_l0[2];
        const int base = lane * COLB;
#pragma unroll
        for (int m = 0; m < 6; ++m) {   // rows 4m..4m+3 (row 23 = bias carrier)
            v2f wiA = L0WI[2 * m], wiB = L0WI[2 * m + 1];
            v2f uA  = __builtin_elementwise_fma(L0WS[2 * m],     Sv, L0BB[2 * m]);
            v2f uB  = __builtin_elementwise_fma(L0WS[2 * m + 1], Sv, L0BB[2 * m + 1]);
            v2f a0 = __builtin_elementwise_max(__builtin_elementwise_fma(wiA, lav, uA), z2);
            v2f b0 = __builtin_elementwise_max(__builtin_elementwise_fma(wiB, lav, uB), z2);
            v2f a1 = __builtin_elementwise_max(__builtin_elementwise_fma(wiA, lbv, uA), z2);
            v2f b1 = __builtin_elementwise_max(__builtin_elementwise_fma(wiB, lbv, uB), z2);
            v2f a2 = __builtin_elementwise_max(__builtin_elementwise_fma(wiA, lcv, uA), z2);
            v2f b2 = __builtin_elementwise_max(__builtin_elementwise_fma(wiB, lcv, uB), z2);
            if (m == 5) b0.y = 1.0f;   // row 23, channel t0: bias carrier = 1.0
            int cb = base + (m >> 1) * 48 + (m & 1) * 8;
            *(f16x4*)(lds + cb +  0) = (f16x4){(_Float16)a0.x, (_Float16)a0.y, (_Float16)b0.x, (_Float16)b0.y};
            *(f16x4*)(lds + cb + 16) = (f16x4){(_Float16)a1.x, (_Float16)a1.y, (_Float16)b1.x, (_Float16)b1.y};
            *(f16x4*)(lds + cb + 32) = (f16x4){(_Float16)a2.x, (_Float16)a2.y, (_Float16)b2.x, (_Float16)b2.y};
        }
    }

    // layer-3 A fragment (4 VGPRs, loop-invariant)
    const f16x8 A3 = *(const f16x8*)(&g_a3frag[lane][0]);

    float eva = 0.0f, evb = 0.0f, evc = 0.0f;
    const f32x4 z4 = {0.f, 0.f, 0.f, 0.f};

    // ---- middle layers + fused layer 3, all on the matrix pipe ----
#pragma unroll
    for (int L = 0; L < 2; ++L) {
        f16x8 WiM0 = *(const f16x8*)(&g_afrag[L][0][0][lane][0]);
        f16x8 WiM1 = *(const f16x8*)(&g_afrag[L][0][1][lane][0]);
        f16x8 WsM0 = *(const f16x8*)(&g_afrag[L][1][0][lane][0]);
        f16x8 WsM1 = *(const f16x8*)(&g_afrag[L][1][1][lane][0]);

#pragma unroll
        for (int pp = 0; pp < 4; ++pp) {          // col-tiles (16 cols each)
            const int colb = (16 * pp + c16) * COLB;
            f16x8 bf[3];
#pragma unroll
            for (int h = 0; h < 3; ++h) {
                int off = (g == 3) ? ZOFF : (colb + g * 48 + h * 16);
                bf[h] = *(const f16x8*)(lds + off);   // one ds_read_b128
            }
            // id path: 6 independent MFMAs
            f32x4 c0m0 = mm16(WiM0, bf[0]);
            f32x4 c0m1 = mm16(WiM1, bf[0]);
            f32x4 c1m0 = mm16(WiM0, bf[1]);
            f32x4 c1m1 = mm16(WiM1, bf[1]);
            f32x4 c2m0 = mm16(WiM0, bf[2]);
            f32x4 c2m1 = mm16(WiM1, bf[2]);
            // sum path: Ws*(t0+t1+t2) + bias (bias col k=23 rides on bf[0])
            f32x4 sm0 = mm16a(WsM0, bf[2], mm16a(WsM0, bf[1], mm16(WsM0, bf[0])));
            f32x4 sm1 = mm16a(WsM1, bf[2], mm16a(WsM1, bf[1], mm16(WsM1, bf[0])));

            // packed epilogue: y_d = relu(c_d + s); write 3 channels back
#pragma unroll
            for (int mt = 0; mt < 2; ++mt) {
                if (mt == 1 && g >= 2) continue;  // rows 24..31 are pad
                f32x4 c0 = (mt == 0) ? c0m0 : c0m1;
                f32x4 c1 = (mt == 0) ? c1m0 : c1m1;
                f32x4 c2 = (mt == 0) ? c2m0 : c2m1;
                f32x4 u  = (mt == 0) ? sm0  : sm1;   // bias already inside
                f32x4 y0 = __builtin_elementwise_max(c0 + u, z4);
                f32x4 y1 = __builtin_elementwise_max(c1 + u, z4);
                f32x4 y2 = __builtin_elementwise_max(c2 + u, z4);
                if (mt == 1 && g == 1) y0[3] = 1.0f;  // re-plant bias carrier (row 23, t0)
                // rows 16mt+4g..+3 -> chunk 2mt+(g>>1), half (g&1)
                int wb = colb + (2 * mt + (g >> 1)) * 48 + (g & 1) * 8;
                *(f16x4*)(lds + wb +  0) = (f16x4){(_Float16)y0[0], (_Float16)y0[1], (_Float16)y0[2], (_Float16)y0[3]};
                *(f16x4*)(lds + wb + 16) = (f16x4){(_Float16)y1[0], (_Float16)y1[1], (_Float16)y1[2], (_Float16)y1[3]};
                *(f16x4*)(lds + wb + 32) = (f16x4){(_Float16)y2[0], (_Float16)y2[1], (_Float16)y2[2], (_Float16)y2[3]};
            }

            // fused layer 3 (after last middle layer): read fresh columns back
            // (same-wave DS => ordered), one MFMA per channel. A3 has zero at
            // k=23, so the bias-carrier 1.0 is inert here.
            if (L == 1) {
                f16x8 b2f[3];
#pragma unroll
                for (int h = 0; h < 3; ++h) {
                    int off = (g == 3) ? ZOFF : (colb + g * 48 + h * 16);
                    b2f[h] = *(const f16x8*)(lds + off);
                }
                f32x4 D0 = mm16(A3, b2f[0]);   // row0: dot(wi3,t0); row1: dot(ws3,t0)
                f32x4 D1 = mm16(A3, b2f[1]);
                f32x4 D2 = mm16(A3, b2f[2]);
                float ssum = D0[1] + D1[1] + D2[1];
                float ea = D0[0] + ssum;
                float eb = D1[0] + ssum;
                float ec = D2[0] + ssum;
                ea = __shfl(ea, c16);          // broadcast from g==0 lane of this col
                eb = __shfl(eb, c16);
                ec = __shfl(ec, c16);
                bool own = (g == pp);          // tile pp holds col == lane for g==pp
                eva = own ? ea : eva;
                evb = own ? eb : evb;
                evc = own ? ec : evc;
            }
        }
    }

    {
        float b3v = bb3[0];
        eva += b3v; evb += b3v; evc += b3v;
    }

    // ---- spectral reconstruction via Newton divided differences ----
    float g1 = (evb - eva) * sinv(lb - la);
    float g2 = (evc - evb) * sinv(lc - lb);
    float c2 = (g2 - g1) * sinv(lc - la);

    float m100 = x00 - la, m111 = x11 - la, m122 = x22 - la;
    float m200 = x00 - lb, m211 = x11 - lb, m222 = x22 - lb;

    float P00 = m100 * m200 + x01 * x01 + x02 * x02;
    float P01 = m100 * x01 + x01 * m211 + x02 * x12;
    float P02 = m100 * x02 + x01 * x12 + x02 * m222;
    float P11 = x01 * x01 + m111 * m211 + x12 * x12;
    float P12 = x01 * x02 + m111 * x12 + x12 * m222;
    float P22 = x02 * x02 + x12 * x12 + m122 * m222;

    float o00 = fmaf(g1, m100, eva) + c2 * P00;
    float o01 = g1 * x01 + c2 * P01;
    float o02 = g1 * x02 + c2 * P02;
    float o11 = fmaf(g1, m111, eva) + c2 * P11;
    float o12 = g1 * x12 + c2 * P12;
    float o22 = fmaf(g1, m122, eva) + c2 * P22;

    if (idx < B) {
        float* op = out + (size_t)idx * 9;
        f4a s0v = {o00, o01, o02, o01};
        f4a s1v = {o11, o12, o02, o12};
        *(f4a*)(op)     = s0v;
        *(f4a*)(op + 4) = s1v;
        op[8] = o22;
    }
}

extern "C" void kernel_launch(void* const* d_in, const int* in_sizes, int n_in,
                              void* d_out, int out_size, void* d_ws, size_t ws_size,
                              hipStream_t stream) {
    const float* x   = (const float*)d_in[0];
    const float* wi0 = (const float*)d_in[1];
    const float* ws0 = (const float*)d_in[2];
    const float* b0  = (const float*)d_in[3];
    const float* wi1 = (const float*)d_in[4];
    const float* ws1 = (const float*)d_in[5];
    const float* b1  = (const float*)d_in[6];
    const float* wi2 = (const float*)d_in[7];
    const float* ws2 = (const float*)d_in[8];
    const float* b2  = (const float*)d_in[9];
    const float* wi3 = (const float*)d_in[10];
    const float* ws3 = (const float*)d_in[11];
    const float* b3  = (const float*)d_in[12];

    int B = in_sizes[0] / 9;
    float* out = (float*)d_out;

    {
        dim3 block(256);
        dim3 grid(2);   // 512 threads cover afrag; subsets pack a3frag + l0
        hipLaunchKernelGGL(svh_prep_kernel, grid, block, 0, stream,
                           wi0, ws0, b0, wi1, ws1, b1, wi2, ws2, b2, wi3, ws3);
    }

    dim3 block(64);
    dim3 grid((B + 63) / 64);
    hipLaunchKernelGGL(svh_eig_mlp_kernel, grid, block, 0, stream,
                       x, b3, out, B);
}

// Round 9
// 118.802 us; speedup vs baseline: 1.0027x; 1.0027x over previous
//
#include <hip/hip_runtime.h>
#include <math.h>

// One thread per batch element for eig + layer0 + reconstruction.
// Middle layers (23x23, id + sum path) and layer 3 run on the MATRIX pipe.
// Each 64-thread block is ONE wave, fully self-contained, no __syncthreads
// (a wave's DS ops execute in order).
//
// CONSOLIDATION round: base = round-5 kernel (verified 117.0us, absmax 0.0156).
// Deltas, all exact or previously verified:
// - vector output stores (2x dwordx4 + dword)  [ran in r7, passed]
// - biases via packed f32 g_bias[2][32] loads (same f32 adds as r5)
// - libm acosf (r6/r7 lesson: minimax polys lose RELATIVE accuracy near r->1,
//   which couples as node_err*(eps_f16/gap) in the spectral reconstruction)
// Shelved: in-register layer 3 (r8 absmax 0.993, unexplained; suspect
// cross-type LDS store/load reordering once layers became separate blocks).

#define MLP_W 23

typedef _Float16 h2    __attribute__((ext_vector_type(2)));
typedef _Float16 f16x4 __attribute__((ext_vector_type(4)));
typedef _Float16 f16x8 __attribute__((ext_vector_type(8)));
typedef float    f32x4 __attribute__((ext_vector_type(4)));
typedef float    v2f   __attribute__((ext_vector_type(2)));
typedef float    f4a   __attribute__((ext_vector_type(4), aligned(4)));

// A-fragments for the two middle layers (mfma_f32_16x16x32_f16):
// lane l holds A[row = mt*16 + (l&15)][k = 8*(l>>4) + e], e=0..7, zero past 22.
__device__ __attribute__((aligned(16))) h2 g_afrag[2][2][2][64][4];
// layer-3 A-fragment: row 0 = wi3, row 1 = ws3, rows 2..15 zero.
__device__ __attribute__((aligned(16))) h2 g_a3frag[64][4];
// middle-layer biases, f32, zero-padded to 32: [layer][row]
__device__ __attribute__((aligned(16))) float g_bias[2][32];
// layer-0 weights, zero-padded to 24 for pair loads: [0]=wi, [1]=ws, [2]=b
__device__ __attribute__((aligned(16))) float g_l0[3][24];

__global__ void svh_prep_kernel(const float* __restrict__ wi0, const float* __restrict__ ws0,
                                const float* __restrict__ b0,
                                const float* __restrict__ wi1, const float* __restrict__ ws1,
                                const float* __restrict__ b1,
                                const float* __restrict__ wi2, const float* __restrict__ ws2,
                                const float* __restrict__ b2,
                                const float* __restrict__ wi3, const float* __restrict__ ws3) {
    int t = blockIdx.x * blockDim.x + threadIdx.x;
    if (t < 512) {   // one thread per [layer][mat][mtile][lane]
        int lane  = t & 63;
        int mt    = (t >> 6) & 1;
        int mat   = (t >> 7) & 1;
        int layer = (t >> 8) & 1;
        const float* W = layer ? (mat ? ws2 : wi2) : (mat ? ws1 : wi1);
        int row = mt * 16 + (lane & 15);
        int g   = lane >> 4;
#pragma unroll
        for (int dw = 0; dw < 4; ++dw) {
            int k0 = 8 * g + 2 * dw, k1 = k0 + 1;
            float a = (row < MLP_W && k0 < MLP_W) ? W[row * MLP_W + k0] : 0.0f;
            float b = (row < MLP_W && k1 < MLP_W) ? W[row * MLP_W + k1] : 0.0f;
            g_afrag[layer][mat][mt][lane][dw] = (h2){(_Float16)a, (_Float16)b};
        }
    }
    if (t < 64) {
        int lane = t;
        int row  = lane & 15;
        int g    = lane >> 4;
#pragma unroll
        for (int dw = 0; dw < 4; ++dw) {
            int k0 = 8 * g + 2 * dw, k1 = k0 + 1;
            float a = 0.0f, b = 0.0f;
            if (row == 0) {
                a = (k0 < MLP_W) ? wi3[k0] : 0.0f;
                b = (k1 < MLP_W) ? wi3[k1] : 0.0f;
            } else if (row == 1) {
                a = (k0 < MLP_W) ? ws3[k0] : 0.0f;
                b = (k1 < MLP_W) ? ws3[k1] : 0.0f;
            }
            g_a3frag[lane][dw] = (h2){(_Float16)a, (_Float16)b};
        }
        // biases: t<64 covers [layer=t>>5][row=t&31]
        int layer = t >> 5, brow = t & 31;
        const float* bb = layer ? b2 : b1;
        g_bias[layer][brow] = (brow < MLP_W) ? bb[brow] : 0.0f;
    }
    if (t < 24) {
        g_l0[0][t] = (t < MLP_W) ? wi0[t] : 0.0f;
        g_l0[1][t] = (t < MLP_W) ? ws0[t] : 0.0f;
        g_l0[2][t] = (t < MLP_W) ? b0[t]  : 0.0f;
    }
}

__device__ __forceinline__ float sinv(float d) {
    return (fabsf(d) > 1e-20f) ? (1.0f / d) : 0.0f;
}

__device__ __forceinline__ f32x4 mm16(f16x8 a, f16x8 b) {
    return __builtin_amdgcn_mfma_f32_16x16x32_f16(a, b, (f32x4){0.f, 0.f, 0.f, 0.f}, 0, 0, 0);
}
__device__ __forceinline__ f32x4 mm16a(f16x8 a, f16x8 b, f32x4 c) {
    return __builtin_amdgcn_mfma_f32_16x16x32_f16(a, b, c, 0, 0, 0);
}

// LDS: per column (=lane), 3 k-chunks x 3 channels x 16B, col stride 144
// (16-aligned). chunk g' holds k=8g'..8g'+7 (f16x8) of channel h at
// col*144 + g'*48 + h*16. k=24..31 fragment group reads a 16B zero block.
#define COLB 144
#define ZOFF (64 * COLB)    // 9216
#define LDSZ (ZOFF + 16)    // 9232

__global__ __launch_bounds__(64, 4)
void svh_eig_mlp_kernel(
    const float* __restrict__ x,
    const float* __restrict__ bb3,
    float* __restrict__ out, int B)
{
    __shared__ alignas(16) unsigned char lds[LDSZ];

    const int lane = threadIdx.x;           // 0..63, one wave per block
    const int g    = lane >> 4;
    const int c16  = lane & 15;
    int idx  = blockIdx.x * 64 + lane;
    int cidx = (idx < B) ? idx : (B - 1);   // NO early return: cooperative MFMA

    const float* xp = x + (size_t)cidx * 9;
    f4a xa = *(const f4a*)(xp);       // x[0..3]
    f4a xb = *(const f4a*)(xp + 4);   // x[4..7]
    float x22 = xp[8];
    float x00 = xa[0], x01 = xa[1], x02 = xa[2];
    float x11 = xb[0], x12 = xb[1];

    // zero block for the k=24..31 fragment group (same-wave DS => ordered)
    if (lane == 0) *(f32x4*)(lds + ZOFF) = (f32x4){0.f, 0.f, 0.f, 0.f};

    // ---- closed-form symmetric 3x3 eigenvalues (trigonometric method) ----
    float q   = (x00 + x11 + x22) * (1.0f / 3.0f);
    float a00 = x00 - q, a11 = x11 - q, a22 = x22 - q;
    float p1  = x01 * x01 + x02 * x02 + x12 * x12;
    float p2  = a00 * a00 + a11 * a11 + a22 * a22 + 2.0f * p1;
    float p   = sqrtf(p2 * (1.0f / 6.0f));
    float ip  = sinv(p);
    float d00 = a00 * ip, d11 = a11 * ip, d22 = a22 * ip;
    float c01 = x01 * ip, c02 = x02 * ip, c12 = x12 * ip;
    float detB = d00 * (d11 * d22 - c12 * c12)
               - c01 * (c01 * d22 - c12 * c02)
               + c02 * (c01 * c12 - d11 * c02);
    float r = 0.5f * detB;
    r = fminf(1.0f, fmaxf(-1.0f, r));
    float phi  = acosf(r) * (1.0f / 3.0f);     // libm: relative-accurate near r=1
    float cph  = __cosf(phi);
    float sph  = sqrtf(fmaxf(0.0f, 1.0f - cph * cph)); // sin(phi) >= 0
    const float SQ3 = 1.7320508075688772f;
    float lc = q + 2.0f * p * cph;
    float la = q - p * cph - SQ3 * p * sph;
    float lb = q - p * cph + SQ3 * p * sph;

    // ---- layer 0 (ic=1): packed-f32 pairs, write own 3-channel column ----
    {
        float S = la + lb + lc;
        v2f Sv = {S, S}, lav = {la, la}, lbv = {lb, lb}, lcv = {lc, lc};
        v2f z2 = {0.f, 0.f};
        const v2f* L0WI = (const v2f*)g_l0[0];
        const v2f* L0WS = (const v2f*)g_l0[1];
        const v2f* L0BB = (const v2f*)g_l0[2];
        const int base = lane * COLB;
#pragma unroll
        for (int m = 0; m < 6; ++m) {   // rows 4m..4m+3 (row 23 pads to 0)
            v2f wiA = L0WI[2 * m], wiB = L0WI[2 * m + 1];
            v2f uA  = __builtin_elementwise_fma(L0WS[2 * m],     Sv, L0BB[2 * m]);
            v2f uB  = __builtin_elementwise_fma(L0WS[2 * m + 1], Sv, L0BB[2 * m + 1]);
            v2f a0 = __builtin_elementwise_max(__builtin_elementwise_fma(wiA, lav, uA), z2);
            v2f b0 = __builtin_elementwise_max(__builtin_elementwise_fma(wiB, lav, uB), z2);
            v2f a1 = __builtin_elementwise_max(__builtin_elementwise_fma(wiA, lbv, uA), z2);
            v2f b1 = __builtin_elementwise_max(__builtin_elementwise_fma(wiB, lbv, uB), z2);
            v2f a2 = __builtin_elementwise_max(__builtin_elementwise_fma(wiA, lcv, uA), z2);
            v2f b2 = __builtin_elementwise_max(__builtin_elementwise_fma(wiB, lcv, uB), z2);
            int cb = base + (m >> 1) * 48 + (m & 1) * 8;
            *(f16x4*)(lds + cb +  0) = (f16x4){(_Float16)a0.x, (_Float16)a0.y, (_Float16)b0.x, (_Float16)b0.y};
            *(f16x4*)(lds + cb + 16) = (f16x4){(_Float16)a1.x, (_Float16)a1.y, (_Float16)b1.x, (_Float16)b1.y};
            *(f16x4*)(lds + cb + 32) = (f16x4){(_Float16)a2.x, (_Float16)a2.y, (_Float16)b2.x, (_Float16)b2.y};
        }
    }

    // layer-3 A fragment (4 VGPRs, loop-invariant)
    const f16x8 A3 = *(const f16x8*)(&g_a3frag[lane][0]);

    float eva = 0.0f, evb = 0.0f, evc = 0.0f;
    const f32x4 z4 = {0.f, 0.f, 0.f, 0.f};

    // ---- middle layers + fused layer 3, all on the matrix pipe ----
#pragma unroll
    for (int L = 0; L < 2; ++L) {
        f16x8 WiM0 = *(const f16x8*)(&g_afrag[L][0][0][lane][0]);
        f16x8 WiM1 = *(const f16x8*)(&g_afrag[L][0][1][lane][0]);
        f16x8 WsM0 = *(const f16x8*)(&g_afrag[L][1][0][lane][0]);
        f16x8 WsM1 = *(const f16x8*)(&g_afrag[L][1][1][lane][0]);
        f32x4 bvec[2];
        bvec[0] = *(const f32x4*)(&g_bias[L][4 * g]);        // rows 4g..4g+3
        bvec[1] = *(const f32x4*)(&g_bias[L][16 + 4 * g]);   // rows 16+4g..+3

#pragma unroll
        for (int pp = 0; pp < 4; ++pp) {          // col-tiles (16 cols each)
            const int colb = (16 * pp + c16) * COLB;
            f16x8 bf[3];
#pragma unroll
            for (int h = 0; h < 3; ++h) {
                int off = (g == 3) ? ZOFF : (colb + g * 48 + h * 16);
                bf[h] = *(const f16x8*)(lds + off);   // one ds_read_b128
            }
            // id path: 6 independent MFMAs
            f32x4 c0m0 = mm16(WiM0, bf[0]);
            f32x4 c0m1 = mm16(WiM1, bf[0]);
            f32x4 c1m0 = mm16(WiM0, bf[1]);
            f32x4 c1m1 = mm16(WiM1, bf[1]);
            f32x4 c2m0 = mm16(WiM0, bf[2]);
            f32x4 c2m1 = mm16(WiM1, bf[2]);
            // sum path: Ws*(t0+t1+t2) via chained accumulate (f32)
            f32x4 sm0 = mm16a(WsM0, bf[2], mm16a(WsM0, bf[1], mm16(WsM0, bf[0])));
            f32x4 sm1 = mm16a(WsM1, bf[2], mm16a(WsM1, bf[1], mm16(WsM1, bf[0])));

            // packed epilogue: u = s + bias; y_d = relu(c_d + u); write back
#pragma unroll
            for (int mt = 0; mt < 2; ++mt) {
                if (mt == 1 && g >= 2) continue;  // rows 24..31 are pad
                f32x4 c0 = (mt == 0) ? c0m0 : c0m1;
                f32x4 c1 = (mt == 0) ? c1m0 : c1m1;
                f32x4 c2 = (mt == 0) ? c2m0 : c2m1;
                f32x4 cs = (mt == 0) ? sm0  : sm1;
                f32x4 u  = cs + bvec[mt];
                f32x4 y0 = __builtin_elementwise_max(c0 + u, z4);
                f32x4 y1 = __builtin_elementwise_max(c1 + u, z4);
                f32x4 y2 = __builtin_elementwise_max(c2 + u, z4);
                // rows 16mt+4g..+3 -> chunk 2mt+(g>>1), half (g&1)
                int wb = colb + (2 * mt + (g >> 1)) * 48 + (g & 1) * 8;
                *(f16x4*)(lds + wb +  0) = (f16x4){(_Float16)y0[0], (_Float16)y0[1], (_Float16)y0[2], (_Float16)y0[3]};
                *(f16x4*)(lds + wb + 16) = (f16x4){(_Float16)y1[0], (_Float16)y1[1], (_Float16)y1[2], (_Float16)y1[3]};
                *(f16x4*)(lds + wb + 32) = (f16x4){(_Float16)y2[0], (_Float16)y2[1], (_Float16)y2[2], (_Float16)y2[3]};
            }

            // fused layer 3 (after last middle layer): read fresh columns back
            // (same-wave DS => ordered), one MFMA per channel.
            if (L == 1) {
                f16x8 b2f[3];
#pragma unroll
                for (int h = 0; h < 3; ++h) {
                    int off = (g == 3) ? ZOFF : (colb + g * 48 + h * 16);
                    b2f[h] = *(const f16x8*)(lds + off);
                }
                f32x4 D0 = mm16(A3, b2f[0]);   // row0: dot(wi3,t0); row1: dot(ws3,t0)
                f32x4 D1 = mm16(A3, b2f[1]);
                f32x4 D2 = mm16(A3, b2f[2]);
                float ssum = D0[1] + D1[1] + D2[1];
                float ea = D0[0] + ssum;
                float eb = D1[0] + ssum;
                float ec = D2[0] + ssum;
                ea = __shfl(ea, c16);          // broadcast from g==0 lane of this col
                eb = __shfl(eb, c16);
                ec = __shfl(ec, c16);
                bool own = (g == pp);          // tile pp holds col == lane for g==pp
                eva = own ? ea : eva;
                evb = own ? eb : evb;
                evc = own ? ec : evc;
            }
        }
    }

    {
        float b3v = bb3[0];
        eva += b3v; evb += b3v; evc += b3v;
    }

    // ---- spectral reconstruction via Newton divided differences ----
    float g1 = (evb - eva) * sinv(lb - la);
    float g2 = (evc - evb) * sinv(lc - lb);
    float c2 = (g2 - g1) * sinv(lc - la);

    float m100 = x00 - la, m111 = x11 - la, m122 = x22 - la;
    float m200 = x00 - lb, m211 = x11 - lb, m222 = x22 - lb;

    float P00 = m100 * m200 + x01 * x01 + x02 * x02;
    float P01 = m100 * x01 + x01 * m211 + x02 * x12;
    float P02 = m100 * x02 + x01 * x12 + x02 * m222;
    float P11 = x01 * x01 + m111 * m211 + x12 * x12;
    float P12 = x01 * x02 + m111 * x12 + x12 * m222;
    float P22 = x02 * x02 + x12 * x12 + m122 * m222;

    float o00 = fmaf(g1, m100, eva) + c2 * P00;
    float o01 = g1 * x01 + c2 * P01;
    float o02 = g1 * x02 + c2 * P02;
    float o11 = fmaf(g1, m111, eva) + c2 * P11;
    float o12 = g1 * x12 + c2 * P12;
    float o22 = fmaf(g1, m122, eva) + c2 * P22;

    if (idx < B) {
        float* op = out + (size_t)idx * 9;
        f4a s0v = {o00, o01, o02, o01};
        f4a s1v = {o11, o12, o02, o12};
        *(f4a*)(op)     = s0v;
        *(f4a*)(op + 4) = s1v;
        op[8] = o22;
    }
}

extern "C" void kernel_launch(void* const* d_in, const int* in_sizes, int n_in,
                              void* d_out, int out_size, void* d_ws, size_t ws_size,
                              hipStream_t stream) {
    const float* x   = (const float*)d_in[0];
    const float* wi0 = (const float*)d_in[1];
    const float* ws0 = (const float*)d_in[2];
    const float* b0  = (const float*)d_in[3];
    const float* wi1 = (const float*)d_in[4];
    const float* ws1 = (const float*)d_in[5];
    const float* b1  = (const float*)d_in[6];
    const float* wi2 = (const float*)d_in[7];
    const float* ws2 = (const float*)d_in[8];
    const float* b2  = (const float*)d_in[9];
    const float* wi3 = (const float*)d_in[10];
    const float* ws3 = (const float*)d_in[11];
    const float* b3  = (const float*)d_in[12];

    int B = in_sizes[0] / 9;
    float* out = (float*)d_out;

    {
        dim3 block(256);
        dim3 grid(2);   // 512 threads cover afrag; subsets pack a3frag/bias/l0
        hipLaunchKernelGGL(svh_prep_kernel, grid, block, 0, stream,
                           wi0, ws0, b0, wi1, ws1, b1, wi2, ws2, b2, wi3, ws3);
    }

    dim3 block(64);
    dim3 grid((B + 63) / 64);
    hipLaunchKernelGGL(svh_eig_mlp_kernel, grid, block, 0, stream,
                       x, b3, out, B);
}